// Round 4
// baseline (680.113 us; speedup 1.0000x reference)
//
#include <hip/hip_runtime.h>
#include <hip/hip_bf16.h>

// ---------------------------------------------------------------------------
// MoE transformer block, MI355X gfx950.
// B=8 S=512 D=768 H=12 dh=64 E=14 K=4 HID=1536 SH=3072
// R4: tanh-GELU epilogue (erff cost 2.4x the MFMA work: VALUBusy56/Mfma20);
//     attn P kept in LDS (swizzled, -100MB HBM); expert2 fused into out via
//     atomics (combine removed); one fused weight-transpose launch.
// ---------------------------------------------------------------------------

typedef _Float16 f16x8 __attribute__((ext_vector_type(8)));
typedef float f32x4 __attribute__((ext_vector_type(4)));
typedef _Float16 f16;

// tanh-form GELU: gelu(x) ~= x * t/(t+1), t = exp(2*0.79788456(x+0.044715x^3))
// max |diff vs exact erf-gelu| ~3e-3; one v_exp_f32 instead of erff's ~30 VALU.
__device__ __forceinline__ float gelu_fast(float x) {
  const float k2l2e = 2.f * 0.7978845608028654f * 1.4426950408889634f;
  float u = (x + 0.044715f * x * x * x) * k2l2e;
  float t = exp2f(u);                  // inf for large u -> result x (ok)
  return x * (1.f - 1.f / (t + 1.f));
}

__device__ __forceinline__ f32x4 mfma16(f16x8 a, f16x8 b, f32x4 c) {
  return __builtin_amdgcn_mfma_f32_16x16x32_f16(a, b, c, 0, 0, 0);
}

// async global->LDS, 16B per lane; LDS dst must be wave-uniform base + lane*16
#define ASYNC_CP16(g, l)                                            \
  __builtin_amdgcn_global_load_lds(                                 \
      (const __attribute__((address_space(1))) void*)(g),           \
      (__attribute__((address_space(3))) void*)(l), 16, 0, 0)

// ---------------------------------------------------------------------------
// LayerNorm: fp32 in -> f16 out, saves per-row mean and rstd (for router).
// ---------------------------------------------------------------------------
__global__ __launch_bounds__(256) void ln_kernel(
    const float* __restrict__ x, const float* __restrict__ g,
    const float* __restrict__ bt, f16* __restrict__ out,
    float* __restrict__ mout, float* __restrict__ rout)
{
  const int row = blockIdx.x;
  const float* xr = x + (long)row * 768;
  const int t = threadIdx.x;
  float v0 = xr[t], v1 = xr[t + 256], v2 = xr[t + 512];
  __shared__ float sb[8];
  float s = v0 + v1 + v2;
  #pragma unroll
  for (int o = 32; o > 0; o >>= 1) s += __shfl_xor(s, o, 64);
  const int w = t >> 6;
  if ((t & 63) == 0) sb[w] = s;
  __syncthreads();
  const float mean = (sb[0] + sb[1] + sb[2] + sb[3]) * (1.0f / 768.0f);
  const float d0 = v0 - mean, d1 = v1 - mean, d2 = v2 - mean;
  float q = d0 * d0 + d1 * d1 + d2 * d2;
  #pragma unroll
  for (int o = 32; o > 0; o >>= 1) q += __shfl_xor(q, o, 64);
  if ((t & 63) == 0) sb[4 + w] = q;
  __syncthreads();
  const float var = (sb[4] + sb[5] + sb[6] + sb[7]) * (1.0f / 768.0f);
  const float rstd = rsqrtf(var + 1e-5f);
  f16* orow = out + (long)row * 768;
  orow[t]       = (f16)(d0 * rstd * g[t]       + bt[t]);
  orow[t + 256] = (f16)(d1 * rstd * g[t + 256] + bt[t + 256]);
  orow[t + 512] = (f16)(d2 * rstd * g[t + 512] + bt[t + 512]);
  if (t == 0) { mout[row] = mean; rout[row] = rstd; }
}

// ---------------------------------------------------------------------------
// Fused transpose of all 6 weight matrices, fp32 [r][c] -> f16 [c][r].
// One launch; descriptor table passed by value.
// ---------------------------------------------------------------------------
struct TransArgs {
  const float* src[6];
  f16* dst[6];
  int rows[6], cols[6];
  int start[7];
};

__global__ __launch_bounds__(256) void transpose_all(TransArgs ta) {
  const int bid = blockIdx.x;
  int m = 0;
  #pragma unroll
  for (int i = 1; i < 6; i++) if (bid >= ta.start[i]) m = i;
  const int rows = ta.rows[m], cols = ta.cols[m];
  const int tilesC = cols >> 5;
  const int perB = (rows >> 5) * tilesC;
  int local = bid - ta.start[m];
  const int z = local / perB; local -= z * perB;
  const int tr = local / tilesC, tc = local - tr * tilesC;
  const float* inb = ta.src[m] + (long)z * rows * cols;
  f16* outb = ta.dst[m] + (long)z * rows * cols;
  const int c0 = tc * 32, r0 = tr * 32;
  __shared__ float tile[32][33];
  const int tx = threadIdx.x & 31, ty = threadIdx.x >> 5;
  #pragma unroll
  for (int i = 0; i < 32; i += 8)
    tile[ty + i][tx] = inb[(long)(r0 + ty + i) * cols + c0 + tx];
  __syncthreads();
  #pragma unroll
  for (int i = 0; i < 32; i += 8)
    outb[(long)(c0 + ty + i) * rows + r0 + tx] = (f16)tile[tx][ty + i];
}

// ---------------------------------------------------------------------------
// Generic GEMM: C[M,N] = A[M,K] @ W^T   (A f16 row-major, W f16 [N][K]).
// 128x128 tile, BK=32, 4 waves x 64x64. Staging via global_load_lds (m97).
// ---------------------------------------------------------------------------
#define EPI_QKV     0
#define EPI_RESID   1
#define EPI_GELU    2
#define EPI_OUTBASE 3   // out = resid + v + bias   (fp32, shared-FFN2)
#define EPI_ATOMIC  4   // atomicAdd(out, w[pair]*(v+bias))  (expert-FFN2)

template <int EPI>
__global__ __launch_bounds__(256) void gemm_bt(
    const f16* __restrict__ A, int K, long strideA, int aShift,
    const f16* __restrict__ W, long strideW,
    const float* __restrict__ bias, int strideBias,
    const int* __restrict__ topkIdx,
    void* __restrict__ outv, long strideOut, int ldout,
    const float* __restrict__ resid)
{
  __shared__ f16 sA[128 * 32];
  __shared__ f16 sB[128 * 32];
  const int tid = threadIdx.x;
  const int pair = blockIdx.z;
  const int m0 = blockIdx.y * 128;
  const int n0 = blockIdx.x * 128;
  const f16* Ab = A + ((long)(pair >> aShift)) * strideA;
  const int wsel = topkIdx ? topkIdx[pair] : pair;
  const f16* Wb = W + (long)wsel * strideW;

  const int f = tid * 8;
  const int fr = f >> 5;
  const int fc = f & 31;
  const int lane = tid & 63, wid = tid >> 6;
  const int wm = (wid >> 1) * 64, wn = (wid & 1) * 64;
  const int lr = lane & 15, q4 = lane >> 4;

  f32x4 zero = {0.f, 0.f, 0.f, 0.f};
  f32x4 acc[4][4];
  #pragma unroll
  for (int i = 0; i < 4; i++)
    #pragma unroll
    for (int j = 0; j < 4; j++) acc[i][j] = zero;

  for (int k0 = 0; k0 < K; k0 += 32) {
    __syncthreads();
    ASYNC_CP16(&Ab[(long)(m0 + fr) * K + k0 + fc],      &sA[f]);
    ASYNC_CP16(&Ab[(long)(m0 + fr + 64) * K + k0 + fc], &sA[f + 2048]);
    ASYNC_CP16(&Wb[(long)(n0 + fr) * K + k0 + fc],      &sB[f]);
    ASYNC_CP16(&Wb[(long)(n0 + fr + 64) * K + k0 + fc], &sB[f + 2048]);
    __syncthreads();
    f16x8 av[4], bv[4];
    #pragma unroll
    for (int i = 0; i < 4; i++) av[i] = *(const f16x8*)&sA[(wm + i * 16 + lr) * 32 + q4 * 8];
    #pragma unroll
    for (int j = 0; j < 4; j++) bv[j] = *(const f16x8*)&sB[(wn + j * 16 + lr) * 32 + q4 * 8];
    #pragma unroll
    for (int i = 0; i < 4; i++)
      #pragma unroll
      for (int j = 0; j < 4; j++) acc[i][j] = mfma16(av[i], bv[j], acc[i][j]);
  }

  float wscale = 0.f;
  if constexpr (EPI == EPI_ATOMIC) wscale = resid[pair];  // resid slot = wslot

  // Epilogue. C/D layout: col = lane&15, row = (lane>>4)*4 + reg.
  #pragma unroll
  for (int i = 0; i < 4; i++) {
    #pragma unroll
    for (int j = 0; j < 4; j++) {
      #pragma unroll
      for (int r = 0; r < 4; r++) {
        const int row = m0 + wm + i * 16 + q4 * 4 + r;
        const int col = n0 + wn + j * 16 + lr;
        float v = acc[i][j][r];
        if constexpr (EPI == EPI_QKV) {
          f16* qb = (f16*)outv;
          const int i3 = col / 768;
          const int rem = col - i3 * 768;
          const int hh = rem >> 6, dd = rem & 63;
          const int bb = row >> 9, ss = row & 511;
          const long bh = bb * 12 + hh;
          if (i3 == 0)      qb[(bh * 512 + ss) * 64 + dd] = (f16)v;           // Q
          else if (i3 == 1) qb[3145728 + (bh * 512 + ss) * 64 + dd] = (f16)v; // K
          else              qb[6291456 + (bh * 64 + dd) * 512 + ss] = (f16)v; // V^T
        } else if constexpr (EPI == EPI_RESID) {
          float* ob = (float*)outv;
          v += bias[col];
          ob[(long)row * ldout + col] = resid[(long)row * ldout + col] + v;
        } else if constexpr (EPI == EPI_GELU) {
          f16* ob = (f16*)outv + (long)pair * strideOut;
          v += bias[(long)wsel * strideBias + col];
          ob[(long)row * ldout + col] = (f16)gelu_fast(v);
        } else if constexpr (EPI == EPI_OUTBASE) {
          float* ob = (float*)outv;
          v += bias[col];
          ob[(long)row * ldout + col] = resid[(long)row * ldout + col] + v;
        } else {  // EPI_ATOMIC
          float* ob = (float*)outv + (long)(pair >> 2) * (512L * 768);
          v += bias[(long)wsel * strideBias + col];
          atomicAdd(&ob[(long)row * ldout + col], wscale * v);
        }
      }
    }
  }
}

// ---------------------------------------------------------------------------
// Fused attention per (b*h, q-tile of 64). P lives in LDS (XOR-swizzled);
// each wave touches only its own 16 q-rows -> no barrier needed.
// ---------------------------------------------------------------------------
__device__ __forceinline__ int pswz(int row, int col) {
  return row * 512 + (col ^ ((row & 7) << 3));
}

__global__ __launch_bounds__(256) void attn_kernel(
    const f16* __restrict__ Q, const f16* __restrict__ Kt,
    const f16* __restrict__ Vt, f16* __restrict__ AO)
{
  __shared__ f16 Ps[64 * 512];         // 64 KB, swizzled
  const int bh = blockIdx.x;
  const int qt = blockIdx.y;
  const int t = threadIdx.x;
  const int lane = t & 63, w = t >> 6;
  const int lr = lane & 15, q4 = lane >> 4;
  const int r0 = qt * 64 + w * 16;
  const int lrow0 = w * 16;            // wave's local row base in Ps
  const f16* Qh = Q + (long)bh * 512 * 64;
  const f16* Kh = Kt + (long)bh * 512 * 64;

  f32x4 zero = {0.f, 0.f, 0.f, 0.f};
  f32x4 acc[32];
  #pragma unroll
  for (int i = 0; i < 32; i++) acc[i] = zero;

  #pragma unroll
  for (int kk = 0; kk < 2; kk++) {
    f16x8 a = *(const f16x8*)&Qh[(r0 + lr) * 64 + kk * 32 + q4 * 8];
    #pragma unroll
    for (int nt = 0; nt < 32; nt++) {
      f16x8 b = *(const f16x8*)&Kh[(nt * 16 + lr) * 64 + kk * 32 + q4 * 8];
      acc[nt] = mfma16(a, b, acc[nt]);
    }
  }

  const float cscale = 0.125f * 1.44269504089f;
  #pragma unroll
  for (int r = 0; r < 4; r++) {
    float m = -1e30f;
    #pragma unroll
    for (int nt = 0; nt < 32; nt++) m = fmaxf(m, acc[nt][r]);
    #pragma unroll
    for (int o = 1; o < 16; o <<= 1) m = fmaxf(m, __shfl_xor(m, o, 64));
    float s = 0.f;
    #pragma unroll
    for (int nt = 0; nt < 32; nt++) {
      float e = exp2f((acc[nt][r] - m) * cscale);
      acc[nt][r] = e; s += e;
    }
    #pragma unroll
    for (int o = 1; o < 16; o <<= 1) s += __shfl_xor(s, o, 64);
    const float inv = 1.f / s;
    const int lrow = lrow0 + q4 * 4 + r;
    #pragma unroll
    for (int nt = 0; nt < 32; nt++)
      Ps[pswz(lrow, nt * 16 + lr)] = (f16)(acc[nt][r] * inv);
  }
  // no __syncthreads: each wave reads back only rows it wrote (lgkmcnt order)

  const f16* Vh = Vt + (long)bh * 64 * 512;
  f32x4 o4[4];
  #pragma unroll
  for (int i = 0; i < 4; i++) o4[i] = zero;
  #pragma unroll
  for (int kk = 0; kk < 16; kk++) {
    f16x8 a = *(const f16x8*)&Ps[pswz(lrow0 + lr, kk * 32 + q4 * 8)];
    #pragma unroll
    for (int nt = 0; nt < 4; nt++) {
      f16x8 b = *(const f16x8*)&Vh[(nt * 16 + lr) * 512 + kk * 32 + q4 * 8];
      o4[nt] = mfma16(a, b, o4[nt]);
    }
  }
  const int b_ = bh / 12, h_ = bh - b_ * 12;
  #pragma unroll
  for (int nt = 0; nt < 4; nt++)
    #pragma unroll
    for (int r = 0; r < 4; r++) {
      const int rowg = r0 + q4 * 4 + r;
      AO[((long)(b_ * 512 + rowg)) * 768 + h_ * 64 + nt * 16 + lr] = (f16)o4[nt][r];
    }
}

// ---------------------------------------------------------------------------
// Router stage 1: partial sums of (x-m)*r over 32-row chunks. part[b][c][768].
// ---------------------------------------------------------------------------
__global__ __launch_bounds__(256) void router_reduce(
    const float* __restrict__ x2, const float* __restrict__ lnm,
    const float* __restrict__ lnr, float* __restrict__ part)
{
  const int c = blockIdx.x, b = blockIdx.y, t = threadIdx.x;
  float a0 = 0.f, a1 = 0.f, a2 = 0.f;
  #pragma unroll 4
  for (int s = 0; s < 32; s++) {
    const long base = (long)b * 512 + c * 32 + s;
    const float m = lnm[base], r = lnr[base];
    const float* xr = x2 + base * 768;
    a0 += (xr[t] - m) * r;
    a1 += (xr[t + 256] - m) * r;
    a2 += (xr[t + 512] - m) * r;
  }
  float* pr = part + ((long)b * 16 + c) * 768;
  pr[t] = a0; pr[t + 256] = a1; pr[t + 512] = a2;
}

// ---------------------------------------------------------------------------
// Router stage 2: fold partials -> seq_repr (fp32, global).
// ---------------------------------------------------------------------------
__global__ __launch_bounds__(256) void router_seq(
    const float* __restrict__ part, const float* __restrict__ g2,
    const float* __restrict__ b2ln, float* __restrict__ seqg)
{
  const int b = blockIdx.x, t = threadIdx.x;
  const float* pb = part + (long)b * 16 * 768;
  #pragma unroll
  for (int i = 0; i < 3; i++) {
    const int j = t + 256 * i;
    float a = 0.f;
    #pragma unroll
    for (int c = 0; c < 16; c++) a += pb[c * 768 + j];
    seqg[b * 768 + j] = a * (1.f / 512.f) * g2[j] + b2ln[j];
  }
}

// ---------------------------------------------------------------------------
// Router stage 3: MLP1 partials over 48-deep d-slices.
// ---------------------------------------------------------------------------
__global__ __launch_bounds__(256) void router_mlp1(
    const float* __restrict__ seqg, const float* __restrict__ rw1,
    float* __restrict__ pmlp)
{
  const int c = blockIdx.x, b = blockIdx.y, t = threadIdx.x;
  const float* sq = seqg + b * 768 + c * 48;
  float a0 = 0.f, a1 = 0.f, a2 = 0.f;
  #pragma unroll 8
  for (int d = 0; d < 48; d++) {
    const float s = sq[d];
    const float* wr = rw1 + (long)(c * 48 + d) * 768;
    a0 += s * wr[t];
    a1 += s * wr[t + 256];
    a2 += s * wr[t + 512];
  }
  float* pr = pmlp + ((long)b * 16 + c) * 768;
  pr[t] = a0; pr[t + 256] = a1; pr[t + 512] = a2;
}

// ---------------------------------------------------------------------------
// Router stage 4: fold MLP1 partials + bias + gelu (exact fp32) -> g1g.
// ---------------------------------------------------------------------------
__global__ __launch_bounds__(256) void router_fold(
    const float* __restrict__ pmlp, const float* __restrict__ rb1,
    float* __restrict__ g1g)
{
  const int b = blockIdx.x, t = threadIdx.x;
  const float* pb = pmlp + (long)b * 16 * 768;
  #pragma unroll
  for (int i = 0; i < 3; i++) {
    const int j = t + 256 * i;
    float a = rb1[j];
    #pragma unroll
    for (int c = 0; c < 16; c++) a += pb[c * 768 + j];
    g1g[b * 768 + j] = 0.5f * a * (1.0f + erff(a * 0.70710678118654752f));
  }
}

// ---------------------------------------------------------------------------
// Router stage 5: logits; softmax; top4; renorm (fp32 exact selection).
// ---------------------------------------------------------------------------
__global__ __launch_bounds__(256) void router_top(
    const float* __restrict__ g1g, const float* __restrict__ rw2,
    const float* __restrict__ rb2, float* __restrict__ wslot,
    int* __restrict__ topkIdx)
{
  __shared__ float lg[14];
  const int b = blockIdx.x, t = threadIdx.x;
  const int e = t >> 4, sub = t & 15;
  if (e < 14) {
    float a = 0.f;
    #pragma unroll
    for (int i = 0; i < 48; i++) {
      const int d = sub + 16 * i;
      a += g1g[b * 768 + d] * rw2[d * 14 + e];
    }
    #pragma unroll
    for (int o = 1; o < 16; o <<= 1) a += __shfl_xor(a, o, 64);
    if (sub == 0) lg[e] = a + rb2[e];
  }
  __syncthreads();
  if (t == 0) {
    float mx = -1e30f;
    for (int ee = 0; ee < 14; ee++) mx = fmaxf(mx, lg[ee]);
    float p[14], s = 0.f;
    for (int ee = 0; ee < 14; ee++) { p[ee] = expf(lg[ee] - mx); s += p[ee]; }
    for (int ee = 0; ee < 14; ee++) p[ee] /= s;
    int idx[4]; float val[4]; bool used[14];
    for (int ee = 0; ee < 14; ee++) used[ee] = false;
    for (int k = 0; k < 4; k++) {
      int best = -1; float bv = -1.f;
      for (int ee = 0; ee < 14; ee++)
        if (!used[ee] && p[ee] > bv) { bv = p[ee]; best = ee; }
      used[best] = true; idx[k] = best; val[k] = bv;
    }
    const float m2 = val[0];
    float ss = 0.f, e4[4];
    for (int k = 0; k < 4; k++) { e4[k] = expf(val[k] - m2); ss += e4[k]; }
    for (int k = 0; k < 4; k++) {
      wslot[b * 4 + k] = e4[k] / ss;
      topkIdx[b * 4 + k] = idx[k];
    }
  }
}

// ---------------------------------------------------------------------------
// Workspace layout (bytes). Weights persistent; activations alias A/B phases.
// Total ~175.6 MB (prev layout used 177.2 and passed).
// ---------------------------------------------------------------------------
static const long OFF_X2    = 0L;                       // 12582912
static const long OFF_LNM   = 12582912L;
static const long OFF_LNR   = OFF_LNM + 16384L;
static const long OFF_WSLOT = OFF_LNR + 16384L;
static const long OFF_TOPK  = OFF_WSLOT + 256L;
static const long OFF_PART  = OFF_TOPK + 256L;          // 393216
static const long OFF_SEQG  = OFF_PART + 393216L;
static const long OFF_PMLP  = OFF_SEQG + 24576L;
static const long OFF_G1G   = OFF_PMLP + 393216L;       // ends 13451776
// persistent transposed weights
static const long W_QKVWT  = 13631488L;                 // 3538944
static const long W_PROJWT = W_QKVWT + 3538944L;        // 1179648
static const long W_EW1T   = W_PROJWT + 1179648L;       // 33030144
static const long W_EW2T   = W_EW1T + 33030144L;        // 33030144
static const long W_SHW1T  = W_EW2T + 33030144L;        // 4718592
static const long W_SHW2T  = W_SHW1T + 4718592L;        // 4718592 -> 93847552
// activation region (phase A aliases phase B)
static const long OFF_ACT  = 93847552L;
static const long A_H1     = OFF_ACT;                   // 6291456
static const long A_Q      = OFF_ACT + 6291456L;        // 3 x 6291456
static const long A_AO     = A_Q + 18874368L;           // 6291456
static const long B_H      = OFF_ACT;                   // 6291456
static const long B_HID    = OFF_ACT + 6291456L;        // 50331648
static const long B_SHID   = B_HID + 50331648L;         // 25165824 -> +81.8MB

extern "C" void kernel_launch(void* const* d_in, const int* in_sizes, int n_in,
                              void* d_out, int out_size, void* d_ws, size_t ws_size,
                              hipStream_t stream) {
  const float* x     = (const float*)d_in[0];
  const float* ln1g  = (const float*)d_in[1];
  const float* ln1b  = (const float*)d_in[2];
  const float* qkvw  = (const float*)d_in[3];
  const float* projw = (const float*)d_in[4];
  const float* projb = (const float*)d_in[5];
  const float* ln2g  = (const float*)d_in[6];
  const float* ln2b  = (const float*)d_in[7];
  const float* rw1   = (const float*)d_in[8];
  const float* rb1   = (const float*)d_in[9];
  const float* rw2   = (const float*)d_in[10];
  const float* rb2   = (const float*)d_in[11];
  const float* ew1   = (const float*)d_in[12];
  const float* eb1   = (const float*)d_in[13];
  const float* ew2   = (const float*)d_in[14];
  const float* eb2   = (const float*)d_in[15];
  const float* shw1  = (const float*)d_in[16];
  const float* shb1  = (const float*)d_in[17];
  const float* shw2  = (const float*)d_in[18];
  const float* shb2  = (const float*)d_in[19];

  char* ws = (char*)d_ws;
  float* x2    = (float*)(ws + OFF_X2);
  float* lnm   = (float*)(ws + OFF_LNM);
  float* lnr   = (float*)(ws + OFF_LNR);
  float* wslot = (float*)(ws + OFF_WSLOT);
  int*   topk  = (int*)(ws + OFF_TOPK);
  float* part  = (float*)(ws + OFF_PART);
  float* seqg  = (float*)(ws + OFF_SEQG);
  float* pmlp  = (float*)(ws + OFF_PMLP);
  float* g1g   = (float*)(ws + OFF_G1G);
  f16* qkvwt  = (f16*)(ws + W_QKVWT);
  f16* projwt = (f16*)(ws + W_PROJWT);
  f16* ew1t   = (f16*)(ws + W_EW1T);
  f16* ew2t   = (f16*)(ws + W_EW2T);
  f16* shw1t  = (f16*)(ws + W_SHW1T);
  f16* shw2t  = (f16*)(ws + W_SHW2T);
  f16* h1     = (f16*)(ws + A_H1);
  f16* Qb     = (f16*)(ws + A_Q);
  f16* aob    = (f16*)(ws + A_AO);
  f16* hbuf   = (f16*)(ws + B_H);
  f16* hid    = (f16*)(ws + B_HID);
  f16* shid   = (f16*)(ws + B_SHID);

  // ---- all weight transposes in one launch ----
  TransArgs ta;
  ta.src[0] = qkvw;  ta.dst[0] = qkvwt;  ta.rows[0] = 768;  ta.cols[0] = 2304;
  ta.src[1] = projw; ta.dst[1] = projwt; ta.rows[1] = 768;  ta.cols[1] = 768;
  ta.src[2] = ew1;   ta.dst[2] = ew1t;   ta.rows[2] = 768;  ta.cols[2] = 1536;
  ta.src[3] = ew2;   ta.dst[3] = ew2t;   ta.rows[3] = 1536; ta.cols[3] = 768;
  ta.src[4] = shw1;  ta.dst[4] = shw1t;  ta.rows[4] = 768;  ta.cols[4] = 3072;
  ta.src[5] = shw2;  ta.dst[5] = shw2t;  ta.rows[5] = 3072; ta.cols[5] = 768;
  ta.start[0] = 0;     ta.start[1] = 1728;  ta.start[2] = 2304;
  ta.start[3] = 18432; ta.start[4] = 34560; ta.start[5] = 36864;
  ta.start[6] = 39168;
  transpose_all<<<39168, 256, 0, stream>>>(ta);

  // ---- Phase A: attention ----
  ln_kernel<<<4096, 256, 0, stream>>>(x, ln1g, ln1b, h1, lnm, lnr);
  gemm_bt<EPI_QKV><<<dim3(18, 32, 1), 256, 0, stream>>>(
      h1, 768, 0, 0, qkvwt, 0, nullptr, 0, nullptr, (void*)Qb, 0, 0, nullptr);
  attn_kernel<<<dim3(96, 8, 1), 256, 0, stream>>>(Qb, Qb + 3145728, Qb + 6291456, aob);
  gemm_bt<EPI_RESID><<<dim3(6, 32, 1), 256, 0, stream>>>(
      aob, 768, 0, 0, projwt, 0, projb, 0, nullptr, (void*)x2, 0, 768, x);

  // ---- Phase B: MoE ----
  ln_kernel<<<4096, 256, 0, stream>>>(x2, ln2g, ln2b, hbuf, lnm, lnr);
  router_reduce<<<dim3(16, 8, 1), 256, 0, stream>>>(x2, lnm, lnr, part);
  router_seq<<<8, 256, 0, stream>>>(part, ln2g, ln2b, seqg);
  router_mlp1<<<dim3(16, 8, 1), 256, 0, stream>>>(seqg, rw1, pmlp);
  router_fold<<<8, 256, 0, stream>>>(pmlp, rb1, g1g);
  router_top<<<8, 256, 0, stream>>>(g1g, rw2, rb2, wslot, topk);
  // shared expert: FFN1 -> shid, FFN2 writes out base = x2 + v + bias
  gemm_bt<EPI_GELU><<<dim3(24, 32, 1), 256, 0, stream>>>(
      hbuf, 768, 0, 0, shw1t, 0, shb1, 0, nullptr, (void*)shid, 0, 3072, nullptr);
  gemm_bt<EPI_OUTBASE><<<dim3(6, 32, 1), 256, 0, stream>>>(
      shid, 3072, 0, 0, shw2t, 0, shb2, 0, nullptr, d_out, 0, 768, x2);
  // routed experts: FFN1 -> hid, FFN2 atomically accumulates into out
  gemm_bt<EPI_GELU><<<dim3(12, 4, 32), 256, 0, stream>>>(
      hbuf, 768, 512L * 768, 2, ew1t, 1536L * 768, eb1, 1536, topk,
      (void*)hid, 512L * 1536, 1536, nullptr);
  gemm_bt<EPI_ATOMIC><<<dim3(6, 4, 32), 256, 0, stream>>>(
      hid, 1536, 512L * 1536, 0, ew2t, 768L * 1536, eb2, 768, topk,
      d_out, 0, 768, wslot);
}

// Round 5
// 661.242 us; speedup vs baseline: 1.0285x; 1.0285x over previous
//
#include <hip/hip_runtime.h>
#include <hip/hip_bf16.h>

// ---------------------------------------------------------------------------
// MoE transformer block, MI355X gfx950.
// B=8 S=512 D=768 H=12 dh=64 E=14 K=4 HID=1536 SH=3072
// R5: atomics reverted (107us: 231MB FETCH from 4x fp32 RMW per element).
//     Routing weight w_k folded into FFN1 epilogue (FFN2 linear) -> expert
//     FFN2 is a plain GEMM into eo, combine = out += sum4(eo). eo aliases
//     shid (shared path ordered first). Keeps R4 wins: fast GELU, LDS attn,
//     fused transpose.
// ---------------------------------------------------------------------------

typedef _Float16 f16x8 __attribute__((ext_vector_type(8)));
typedef float f32x4 __attribute__((ext_vector_type(4)));
typedef _Float16 f16;

// tanh-form GELU: one v_exp_f32; |diff vs erf-gelu| <= ~3e-3.
__device__ __forceinline__ float gelu_fast(float x) {
  const float k2l2e = 2.f * 0.7978845608028654f * 1.4426950408889634f;
  float u = (x + 0.044715f * x * x * x) * k2l2e;
  float t = exp2f(u);
  return x * (1.f - 1.f / (t + 1.f));
}

__device__ __forceinline__ f32x4 mfma16(f16x8 a, f16x8 b, f32x4 c) {
  return __builtin_amdgcn_mfma_f32_16x16x32_f16(a, b, c, 0, 0, 0);
}

// async global->LDS, 16B per lane; LDS dst must be wave-uniform base + lane*16
#define ASYNC_CP16(g, l)                                            \
  __builtin_amdgcn_global_load_lds(                                 \
      (const __attribute__((address_space(1))) void*)(g),           \
      (__attribute__((address_space(3))) void*)(l), 16, 0, 0)

// ---------------------------------------------------------------------------
// LayerNorm: fp32 in -> f16 out, saves per-row mean and rstd (for router).
// ---------------------------------------------------------------------------
__global__ __launch_bounds__(256) void ln_kernel(
    const float* __restrict__ x, const float* __restrict__ g,
    const float* __restrict__ bt, f16* __restrict__ out,
    float* __restrict__ mout, float* __restrict__ rout)
{
  const int row = blockIdx.x;
  const float* xr = x + (long)row * 768;
  const int t = threadIdx.x;
  float v0 = xr[t], v1 = xr[t + 256], v2 = xr[t + 512];
  __shared__ float sb[8];
  float s = v0 + v1 + v2;
  #pragma unroll
  for (int o = 32; o > 0; o >>= 1) s += __shfl_xor(s, o, 64);
  const int w = t >> 6;
  if ((t & 63) == 0) sb[w] = s;
  __syncthreads();
  const float mean = (sb[0] + sb[1] + sb[2] + sb[3]) * (1.0f / 768.0f);
  const float d0 = v0 - mean, d1 = v1 - mean, d2 = v2 - mean;
  float q = d0 * d0 + d1 * d1 + d2 * d2;
  #pragma unroll
  for (int o = 32; o > 0; o >>= 1) q += __shfl_xor(q, o, 64);
  if ((t & 63) == 0) sb[4 + w] = q;
  __syncthreads();
  const float var = (sb[4] + sb[5] + sb[6] + sb[7]) * (1.0f / 768.0f);
  const float rstd = rsqrtf(var + 1e-5f);
  f16* orow = out + (long)row * 768;
  orow[t]       = (f16)(d0 * rstd * g[t]       + bt[t]);
  orow[t + 256] = (f16)(d1 * rstd * g[t + 256] + bt[t + 256]);
  orow[t + 512] = (f16)(d2 * rstd * g[t + 512] + bt[t + 512]);
  if (t == 0) { mout[row] = mean; rout[row] = rstd; }
}

// ---------------------------------------------------------------------------
// Fused transpose of all 6 weight matrices, fp32 [r][c] -> f16 [c][r].
// ---------------------------------------------------------------------------
struct TransArgs {
  const float* src[6];
  f16* dst[6];
  int rows[6], cols[6];
  int start[7];
};

__global__ __launch_bounds__(256) void transpose_all(TransArgs ta) {
  const int bid = blockIdx.x;
  int m = 0;
  #pragma unroll
  for (int i = 1; i < 6; i++) if (bid >= ta.start[i]) m = i;
  const int rows = ta.rows[m], cols = ta.cols[m];
  const int tilesC = cols >> 5;
  const int perB = (rows >> 5) * tilesC;
  int local = bid - ta.start[m];
  const int z = local / perB; local -= z * perB;
  const int tr = local / tilesC, tc = local - tr * tilesC;
  const float* inb = ta.src[m] + (long)z * rows * cols;
  f16* outb = ta.dst[m] + (long)z * rows * cols;
  const int c0 = tc * 32, r0 = tr * 32;
  __shared__ float tile[32][33];
  const int tx = threadIdx.x & 31, ty = threadIdx.x >> 5;
  #pragma unroll
  for (int i = 0; i < 32; i += 8)
    tile[ty + i][tx] = inb[(long)(r0 + ty + i) * cols + c0 + tx];
  __syncthreads();
  #pragma unroll
  for (int i = 0; i < 32; i += 8)
    outb[(long)(c0 + ty + i) * rows + r0 + tx] = (f16)tile[tx][ty + i];
}

// ---------------------------------------------------------------------------
// Generic GEMM: C[M,N] = A[M,K] @ W^T   (A f16 row-major, W f16 [N][K]).
// 128x128 tile, BK=32, 4 waves x 64x64. Staging via global_load_lds (m97).
// ---------------------------------------------------------------------------
#define EPI_QKV     0
#define EPI_RESID   1
#define EPI_GELU    2   // f16 out = gelu(v + bias[col])             (shared-FFN1)
#define EPI_OUTBASE 3   // fp32 out = resid + v + bias               (shared-FFN2)
#define EPI_GELUW   4   // f16 out = w[pair]*gelu(v + bias[e][col])  (expert-FFN1)
#define EPI_SCB     5   // f16 out = v + w[pair]*bias[e][col]        (expert-FFN2)

template <int EPI>
__global__ __launch_bounds__(256) void gemm_bt(
    const f16* __restrict__ A, int K, long strideA, int aShift,
    const f16* __restrict__ W, long strideW,
    const float* __restrict__ bias, int strideBias,
    const int* __restrict__ topkIdx,
    void* __restrict__ outv, long strideOut, int ldout,
    const float* __restrict__ resid)
{
  __shared__ f16 sA[128 * 32];
  __shared__ f16 sB[128 * 32];
  const int tid = threadIdx.x;
  const int pair = blockIdx.z;
  const int m0 = blockIdx.y * 128;
  const int n0 = blockIdx.x * 128;
  const f16* Ab = A + ((long)(pair >> aShift)) * strideA;
  const int wsel = topkIdx ? topkIdx[pair] : pair;
  const f16* Wb = W + (long)wsel * strideW;

  const int f = tid * 8;
  const int fr = f >> 5;
  const int fc = f & 31;
  const int lane = tid & 63, wid = tid >> 6;
  const int wm = (wid >> 1) * 64, wn = (wid & 1) * 64;
  const int lr = lane & 15, q4 = lane >> 4;

  f32x4 zero = {0.f, 0.f, 0.f, 0.f};
  f32x4 acc[4][4];
  #pragma unroll
  for (int i = 0; i < 4; i++)
    #pragma unroll
    for (int j = 0; j < 4; j++) acc[i][j] = zero;

  for (int k0 = 0; k0 < K; k0 += 32) {
    __syncthreads();
    ASYNC_CP16(&Ab[(long)(m0 + fr) * K + k0 + fc],      &sA[f]);
    ASYNC_CP16(&Ab[(long)(m0 + fr + 64) * K + k0 + fc], &sA[f + 2048]);
    ASYNC_CP16(&Wb[(long)(n0 + fr) * K + k0 + fc],      &sB[f]);
    ASYNC_CP16(&Wb[(long)(n0 + fr + 64) * K + k0 + fc], &sB[f + 2048]);
    __syncthreads();
    f16x8 av[4], bv[4];
    #pragma unroll
    for (int i = 0; i < 4; i++) av[i] = *(const f16x8*)&sA[(wm + i * 16 + lr) * 32 + q4 * 8];
    #pragma unroll
    for (int j = 0; j < 4; j++) bv[j] = *(const f16x8*)&sB[(wn + j * 16 + lr) * 32 + q4 * 8];
    #pragma unroll
    for (int i = 0; i < 4; i++)
      #pragma unroll
      for (int j = 0; j < 4; j++) acc[i][j] = mfma16(av[i], bv[j], acc[i][j]);
  }

  float wscale = 1.f;
  if constexpr (EPI == EPI_GELUW || EPI == EPI_SCB) wscale = resid[pair];

  // Epilogue. C/D layout: col = lane&15, row = (lane>>4)*4 + reg.
  #pragma unroll
  for (int i = 0; i < 4; i++) {
    #pragma unroll
    for (int j = 0; j < 4; j++) {
      #pragma unroll
      for (int r = 0; r < 4; r++) {
        const int row = m0 + wm + i * 16 + q4 * 4 + r;
        const int col = n0 + wn + j * 16 + lr;
        float v = acc[i][j][r];
        if constexpr (EPI == EPI_QKV) {
          f16* qb = (f16*)outv;
          const int i3 = col / 768;
          const int rem = col - i3 * 768;
          const int hh = rem >> 6, dd = rem & 63;
          const int bb = row >> 9, ss = row & 511;
          const long bh = bb * 12 + hh;
          if (i3 == 0)      qb[(bh * 512 + ss) * 64 + dd] = (f16)v;           // Q
          else if (i3 == 1) qb[3145728 + (bh * 512 + ss) * 64 + dd] = (f16)v; // K
          else              qb[6291456 + (bh * 64 + dd) * 512 + ss] = (f16)v; // V^T
        } else if constexpr (EPI == EPI_RESID) {
          float* ob = (float*)outv;
          v += bias[col];
          ob[(long)row * ldout + col] = resid[(long)row * ldout + col] + v;
        } else if constexpr (EPI == EPI_GELU) {
          f16* ob = (f16*)outv + (long)pair * strideOut;
          v += bias[(long)wsel * strideBias + col];
          ob[(long)row * ldout + col] = (f16)gelu_fast(v);
        } else if constexpr (EPI == EPI_OUTBASE) {
          float* ob = (float*)outv;
          v += bias[col];
          ob[(long)row * ldout + col] = resid[(long)row * ldout + col] + v;
        } else if constexpr (EPI == EPI_GELUW) {
          f16* ob = (f16*)outv + (long)pair * strideOut;
          v += bias[(long)wsel * strideBias + col];
          ob[(long)row * ldout + col] = (f16)(gelu_fast(v) * wscale);
        } else {  // EPI_SCB
          f16* ob = (f16*)outv + (long)pair * strideOut;
          v += wscale * bias[(long)wsel * strideBias + col];
          ob[(long)row * ldout + col] = (f16)v;
        }
      }
    }
  }
}

// ---------------------------------------------------------------------------
// Fused attention per (b*h, q-tile of 64). P lives in LDS (XOR-swizzled);
// each wave touches only its own 16 q-rows -> no barrier needed.
// ---------------------------------------------------------------------------
__device__ __forceinline__ int pswz(int row, int col) {
  return row * 512 + (col ^ ((row & 7) << 3));
}

__global__ __launch_bounds__(256) void attn_kernel(
    const f16* __restrict__ Q, const f16* __restrict__ Kt,
    const f16* __restrict__ Vt, f16* __restrict__ AO)
{
  __shared__ f16 Ps[64 * 512];
  const int bh = blockIdx.x;
  const int qt = blockIdx.y;
  const int t = threadIdx.x;
  const int lane = t & 63, w = t >> 6;
  const int lr = lane & 15, q4 = lane >> 4;
  const int r0 = qt * 64 + w * 16;
  const int lrow0 = w * 16;
  const f16* Qh = Q + (long)bh * 512 * 64;
  const f16* Kh = Kt + (long)bh * 512 * 64;

  f32x4 zero = {0.f, 0.f, 0.f, 0.f};
  f32x4 acc[32];
  #pragma unroll
  for (int i = 0; i < 32; i++) acc[i] = zero;

  #pragma unroll
  for (int kk = 0; kk < 2; kk++) {
    f16x8 a = *(const f16x8*)&Qh[(r0 + lr) * 64 + kk * 32 + q4 * 8];
    #pragma unroll
    for (int nt = 0; nt < 32; nt++) {
      f16x8 b = *(const f16x8*)&Kh[(nt * 16 + lr) * 64 + kk * 32 + q4 * 8];
      acc[nt] = mfma16(a, b, acc[nt]);
    }
  }

  const float cscale = 0.125f * 1.44269504089f;
  #pragma unroll
  for (int r = 0; r < 4; r++) {
    float m = -1e30f;
    #pragma unroll
    for (int nt = 0; nt < 32; nt++) m = fmaxf(m, acc[nt][r]);
    #pragma unroll
    for (int o = 1; o < 16; o <<= 1) m = fmaxf(m, __shfl_xor(m, o, 64));
    float s = 0.f;
    #pragma unroll
    for (int nt = 0; nt < 32; nt++) {
      float e = exp2f((acc[nt][r] - m) * cscale);
      acc[nt][r] = e; s += e;
    }
    #pragma unroll
    for (int o = 1; o < 16; o <<= 1) s += __shfl_xor(s, o, 64);
    const float inv = 1.f / s;
    const int lrow = lrow0 + q4 * 4 + r;
    #pragma unroll
    for (int nt = 0; nt < 32; nt++)
      Ps[pswz(lrow, nt * 16 + lr)] = (f16)(acc[nt][r] * inv);
  }

  const f16* Vh = Vt + (long)bh * 64 * 512;
  f32x4 o4[4];
  #pragma unroll
  for (int i = 0; i < 4; i++) o4[i] = zero;
  #pragma unroll
  for (int kk = 0; kk < 16; kk++) {
    f16x8 a = *(const f16x8*)&Ps[pswz(lrow0 + lr, kk * 32 + q4 * 8)];
    #pragma unroll
    for (int nt = 0; nt < 4; nt++) {
      f16x8 b = *(const f16x8*)&Vh[(nt * 16 + lr) * 512 + kk * 32 + q4 * 8];
      o4[nt] = mfma16(a, b, o4[nt]);
    }
  }
  const int b_ = bh / 12, h_ = bh - b_ * 12;
  #pragma unroll
  for (int nt = 0; nt < 4; nt++)
    #pragma unroll
    for (int r = 0; r < 4; r++) {
      const int rowg = r0 + q4 * 4 + r;
      AO[((long)(b_ * 512 + rowg)) * 768 + h_ * 64 + nt * 16 + lr] = (f16)o4[nt][r];
    }
}

// ---------------------------------------------------------------------------
// Router stage 1: partial sums of (x-m)*r over 32-row chunks. part[b][c][768].
// ---------------------------------------------------------------------------
__global__ __launch_bounds__(256) void router_reduce(
    const float* __restrict__ x2, const float* __restrict__ lnm,
    const float* __restrict__ lnr, float* __restrict__ part)
{
  const int c = blockIdx.x, b = blockIdx.y, t = threadIdx.x;
  float a0 = 0.f, a1 = 0.f, a2 = 0.f;
  #pragma unroll 4
  for (int s = 0; s < 32; s++) {
    const long base = (long)b * 512 + c * 32 + s;
    const float m = lnm[base], r = lnr[base];
    const float* xr = x2 + base * 768;
    a0 += (xr[t] - m) * r;
    a1 += (xr[t + 256] - m) * r;
    a2 += (xr[t + 512] - m) * r;
  }
  float* pr = part + ((long)b * 16 + c) * 768;
  pr[t] = a0; pr[t + 256] = a1; pr[t + 512] = a2;
}

// ---------------------------------------------------------------------------
// Router stage 2: fold partials -> seq_repr (fp32, global).
// ---------------------------------------------------------------------------
__global__ __launch_bounds__(256) void router_seq(
    const float* __restrict__ part, const float* __restrict__ g2,
    const float* __restrict__ b2ln, float* __restrict__ seqg)
{
  const int b = blockIdx.x, t = threadIdx.x;
  const float* pb = part + (long)b * 16 * 768;
  #pragma unroll
  for (int i = 0; i < 3; i++) {
    const int j = t + 256 * i;
    float a = 0.f;
    #pragma unroll
    for (int c = 0; c < 16; c++) a += pb[c * 768 + j];
    seqg[b * 768 + j] = a * (1.f / 512.f) * g2[j] + b2ln[j];
  }
}

// ---------------------------------------------------------------------------
// Router stage 3: MLP1 partials over 48-deep d-slices.
// ---------------------------------------------------------------------------
__global__ __launch_bounds__(256) void router_mlp1(
    const float* __restrict__ seqg, const float* __restrict__ rw1,
    float* __restrict__ pmlp)
{
  const int c = blockIdx.x, b = blockIdx.y, t = threadIdx.x;
  const float* sq = seqg + b * 768 + c * 48;
  float a0 = 0.f, a1 = 0.f, a2 = 0.f;
  #pragma unroll 8
  for (int d = 0; d < 48; d++) {
    const float s = sq[d];
    const float* wr = rw1 + (long)(c * 48 + d) * 768;
    a0 += s * wr[t];
    a1 += s * wr[t + 256];
    a2 += s * wr[t + 512];
  }
  float* pr = pmlp + ((long)b * 16 + c) * 768;
  pr[t] = a0; pr[t + 256] = a1; pr[t + 512] = a2;
}

// ---------------------------------------------------------------------------
// Router stage 4: fold MLP1 partials + bias + gelu (exact fp32) -> g1g.
// ---------------------------------------------------------------------------
__global__ __launch_bounds__(256) void router_fold(
    const float* __restrict__ pmlp, const float* __restrict__ rb1,
    float* __restrict__ g1g)
{
  const int b = blockIdx.x, t = threadIdx.x;
  const float* pb = pmlp + (long)b * 16 * 768;
  #pragma unroll
  for (int i = 0; i < 3; i++) {
    const int j = t + 256 * i;
    float a = rb1[j];
    #pragma unroll
    for (int c = 0; c < 16; c++) a += pb[c * 768 + j];
    g1g[b * 768 + j] = 0.5f * a * (1.0f + erff(a * 0.70710678118654752f));
  }
}

// ---------------------------------------------------------------------------
// Router stage 5: logits; softmax; top4; renorm (fp32 exact selection).
// ---------------------------------------------------------------------------
__global__ __launch_bounds__(256) void router_top(
    const float* __restrict__ g1g, const float* __restrict__ rw2,
    const float* __restrict__ rb2, float* __restrict__ wslot,
    int* __restrict__ topkIdx)
{
  __shared__ float lg[14];
  const int b = blockIdx.x, t = threadIdx.x;
  const int e = t >> 4, sub = t & 15;
  if (e < 14) {
    float a = 0.f;
    #pragma unroll
    for (int i = 0; i < 48; i++) {
      const int d = sub + 16 * i;
      a += g1g[b * 768 + d] * rw2[d * 14 + e];
    }
    #pragma unroll
    for (int o = 1; o < 16; o <<= 1) a += __shfl_xor(a, o, 64);
    if (sub == 0) lg[e] = a + rb2[e];
  }
  __syncthreads();
  if (t == 0) {
    float mx = -1e30f;
    for (int ee = 0; ee < 14; ee++) mx = fmaxf(mx, lg[ee]);
    float p[14], s = 0.f;
    for (int ee = 0; ee < 14; ee++) { p[ee] = expf(lg[ee] - mx); s += p[ee]; }
    for (int ee = 0; ee < 14; ee++) p[ee] /= s;
    int idx[4]; float val[4]; bool used[14];
    for (int ee = 0; ee < 14; ee++) used[ee] = false;
    for (int k = 0; k < 4; k++) {
      int best = -1; float bv = -1.f;
      for (int ee = 0; ee < 14; ee++)
        if (!used[ee] && p[ee] > bv) { bv = p[ee]; best = ee; }
      used[best] = true; idx[k] = best; val[k] = bv;
    }
    const float m2 = val[0];
    float ss = 0.f, e4[4];
    for (int k = 0; k < 4; k++) { e4[k] = expf(val[k] - m2); ss += e4[k]; }
    for (int k = 0; k < 4; k++) {
      wslot[b * 4 + k] = e4[k] / ss;
      topkIdx[b * 4 + k] = idx[k];
    }
  }
}

// ---------------------------------------------------------------------------
// Final combine: out += eo0+eo1+eo2+eo3 (out already = x2 + shared + bias).
// ---------------------------------------------------------------------------
__global__ __launch_bounds__(256) void combine_kernel(
    const f16* __restrict__ eo, float* __restrict__ out)
{
  const long i = (long)blockIdx.x * 256 + threadIdx.x;
  const long b = i / (512L * 768);
  const long loc = i - b * (512L * 768);
  const f16* e0 = eo + b * 4 * (512L * 768) + loc;
  float v = out[i];
  v += (float)e0[0] + (float)e0[512L * 768] + (float)e0[2 * 512L * 768] +
       (float)e0[3 * 512L * 768];
  out[i] = v;
}

// ---------------------------------------------------------------------------
// Workspace layout (bytes). Weights persistent; activations alias.
// Total ~175.6 MB.
// ---------------------------------------------------------------------------
static const long OFF_X2    = 0L;                       // 12582912
static const long OFF_LNM   = 12582912L;
static const long OFF_LNR   = OFF_LNM + 16384L;
static const long OFF_WSLOT = OFF_LNR + 16384L;
static const long OFF_TOPK  = OFF_WSLOT + 256L;
static const long OFF_PART  = OFF_TOPK + 256L;          // 393216
static const long OFF_SEQG  = OFF_PART + 393216L;
static const long OFF_PMLP  = OFF_SEQG + 24576L;
static const long OFF_G1G   = OFF_PMLP + 393216L;       // ends 13451776
// persistent transposed weights
static const long W_QKVWT  = 13631488L;                 // 3538944
static const long W_PROJWT = W_QKVWT + 3538944L;        // 1179648
static const long W_EW1T   = W_PROJWT + 1179648L;       // 33030144
static const long W_EW2T   = W_EW1T + 33030144L;        // 33030144
static const long W_SHW1T  = W_EW2T + 33030144L;        // 4718592
static const long W_SHW2T  = W_SHW1T + 4718592L;        // 4718592 -> 93847552
// activation region (phase A aliases phase B)
static const long OFF_ACT  = 93847552L;
static const long A_H1     = OFF_ACT;                   // 6291456
static const long A_Q      = OFF_ACT + 6291456L;        // 3 x 6291456
static const long A_AO     = A_Q + 18874368L;           // 6291456
static const long B_H      = OFF_ACT;                   // 6291456
static const long B_HID    = OFF_ACT + 6291456L;        // 50331648
static const long B_SHID   = B_HID + 50331648L;         // 25165824
static const long B_EO     = B_SHID;                    // aliases shid (done)

extern "C" void kernel_launch(void* const* d_in, const int* in_sizes, int n_in,
                              void* d_out, int out_size, void* d_ws, size_t ws_size,
                              hipStream_t stream) {
  const float* x     = (const float*)d_in[0];
  const float* ln1g  = (const float*)d_in[1];
  const float* ln1b  = (const float*)d_in[2];
  const float* qkvw  = (const float*)d_in[3];
  const float* projw = (const float*)d_in[4];
  const float* projb = (const float*)d_in[5];
  const float* ln2g  = (const float*)d_in[6];
  const float* ln2b  = (const float*)d_in[7];
  const float* rw1   = (const float*)d_in[8];
  const float* rb1   = (const float*)d_in[9];
  const float* rw2   = (const float*)d_in[10];
  const float* rb2   = (const float*)d_in[11];
  const float* ew1   = (const float*)d_in[12];
  const float* eb1   = (const float*)d_in[13];
  const float* ew2   = (const float*)d_in[14];
  const float* eb2   = (const float*)d_in[15];
  const float* shw1  = (const float*)d_in[16];
  const float* shb1  = (const float*)d_in[17];
  const float* shw2  = (const float*)d_in[18];
  const float* shb2  = (const float*)d_in[19];

  char* ws = (char*)d_ws;
  float* x2    = (float*)(ws + OFF_X2);
  float* lnm   = (float*)(ws + OFF_LNM);
  float* lnr   = (float*)(ws + OFF_LNR);
  float* wslot = (float*)(ws + OFF_WSLOT);
  int*   topk  = (int*)(ws + OFF_TOPK);
  float* part  = (float*)(ws + OFF_PART);
  float* seqg  = (float*)(ws + OFF_SEQG);
  float* pmlp  = (float*)(ws + OFF_PMLP);
  float* g1g   = (float*)(ws + OFF_G1G);
  f16* qkvwt  = (f16*)(ws + W_QKVWT);
  f16* projwt = (f16*)(ws + W_PROJWT);
  f16* ew1t   = (f16*)(ws + W_EW1T);
  f16* ew2t   = (f16*)(ws + W_EW2T);
  f16* shw1t  = (f16*)(ws + W_SHW1T);
  f16* shw2t  = (f16*)(ws + W_SHW2T);
  f16* h1     = (f16*)(ws + A_H1);
  f16* Qb     = (f16*)(ws + A_Q);
  f16* aob    = (f16*)(ws + A_AO);
  f16* hbuf   = (f16*)(ws + B_H);
  f16* hid    = (f16*)(ws + B_HID);
  f16* shid   = (f16*)(ws + B_SHID);
  f16* eo     = (f16*)(ws + B_EO);

  // ---- all weight transposes in one launch ----
  TransArgs ta;
  ta.src[0] = qkvw;  ta.dst[0] = qkvwt;  ta.rows[0] = 768;  ta.cols[0] = 2304;
  ta.src[1] = projw; ta.dst[1] = projwt; ta.rows[1] = 768;  ta.cols[1] = 768;
  ta.src[2] = ew1;   ta.dst[2] = ew1t;   ta.rows[2] = 768;  ta.cols[2] = 1536;
  ta.src[3] = ew2;   ta.dst[3] = ew2t;   ta.rows[3] = 1536; ta.cols[3] = 768;
  ta.src[4] = shw1;  ta.dst[4] = shw1t;  ta.rows[4] = 768;  ta.cols[4] = 3072;
  ta.src[5] = shw2;  ta.dst[5] = shw2t;  ta.rows[5] = 3072; ta.cols[5] = 768;
  ta.start[0] = 0;     ta.start[1] = 1728;  ta.start[2] = 2304;
  ta.start[3] = 18432; ta.start[4] = 34560; ta.start[5] = 36864;
  ta.start[6] = 39168;
  transpose_all<<<39168, 256, 0, stream>>>(ta);

  // ---- Phase A: attention ----
  ln_kernel<<<4096, 256, 0, stream>>>(x, ln1g, ln1b, h1, lnm, lnr);
  gemm_bt<EPI_QKV><<<dim3(18, 32, 1), 256, 0, stream>>>(
      h1, 768, 0, 0, qkvwt, 0, nullptr, 0, nullptr, (void*)Qb, 0, 0, nullptr);
  attn_kernel<<<dim3(96, 8, 1), 256, 0, stream>>>(Qb, Qb + 3145728, Qb + 6291456, aob);
  gemm_bt<EPI_RESID><<<dim3(6, 32, 1), 256, 0, stream>>>(
      aob, 768, 0, 0, projwt, 0, projb, 0, nullptr, (void*)x2, 0, 768, x);

  // ---- Phase B: MoE ----
  ln_kernel<<<4096, 256, 0, stream>>>(x2, ln2g, ln2b, hbuf, lnm, lnr);
  router_reduce<<<dim3(16, 8, 1), 256, 0, stream>>>(x2, lnm, lnr, part);
  router_seq<<<8, 256, 0, stream>>>(part, ln2g, ln2b, seqg);
  router_mlp1<<<dim3(16, 8, 1), 256, 0, stream>>>(seqg, rw1, pmlp);
  router_fold<<<8, 256, 0, stream>>>(pmlp, rb1, g1g);
  router_top<<<8, 256, 0, stream>>>(g1g, rw2, rb2, wslot, topk);
  // shared expert first (shid freed -> eo aliases it)
  gemm_bt<EPI_GELU><<<dim3(24, 32, 1), 256, 0, stream>>>(
      hbuf, 768, 0, 0, shw1t, 0, shb1, 0, nullptr, (void*)shid, 0, 3072, nullptr);
  gemm_bt<EPI_OUTBASE><<<dim3(6, 32, 1), 256, 0, stream>>>(
      shid, 3072, 0, 0, shw2t, 0, shb2, 0, nullptr, d_out, 0, 768, x2);
  // routed experts: FFN1 (w_k folded in) -> hid, FFN2 plain -> eo
  gemm_bt<EPI_GELUW><<<dim3(12, 4, 32), 256, 0, stream>>>(
      hbuf, 768, 512L * 768, 2, ew1t, 1536L * 768, eb1, 1536, topk,
      (void*)hid, 512L * 1536, 1536, wslot);
  gemm_bt<EPI_SCB><<<dim3(6, 4, 32), 256, 0, stream>>>(
      hid, 1536, 512L * 1536, 0, ew2t, 768L * 1536, eb2, 768, topk,
      (void*)eo, 512L * 768, 768, wslot);
  combine_kernel<<<12288, 256, 0, stream>>>(eo, (float*)d_out);
}